// Round 6
// baseline (94.052 us; speedup 1.0000x reference)
//
#include <hip/hip_runtime.h>
#include <math.h>

#define IMH 512
#define IMW 512
#define RB    32    // output rows per wave-band
#define NBAND 16    // IMH / RB
#define NWC   10    // wave-columns: out width 56 each, c0 = 56*wc - 4
#define OUTW  56

__device__ __forceinline__ int reflect_i(int v, int n) {
    if (v < 0) v = -v;
    if (v >= n) v = 2 * n - 2 - v;
    return v;
}

// One wave = one 64-col x RB-row band. lane = column (cx = c0+lane).
// Rolling register pipeline, no LDS, no barriers. 4-row A/B load double-buffer:
// a 12-load burst is issued a full 4-row compute block (~700 cyc) before use.
__global__ __launch_bounds__(256)
void canny_stream(const float* __restrict__ data, float* __restrict__ out) {
    const int lane = threadIdx.x & 63;
    const int wid  = (blockIdx.x << 2) + (threadIdx.x >> 6);
    const int wc   = wid % NWC;
    const int t2   = wid / NWC;
    const int band = t2 & (NBAND - 1);
    const int bat  = t2 >> 4;

    const int c0 = OUTW * wc - 4;
    const int cx = c0 + lane;
    const int y0 = band * RB;

    const size_t plane = (size_t)(IMH * IMW);
    const float* p0 = data + (size_t)bat * 3 * plane;
    const float* p1 = p0 + plane;
    const float* p2 = p1 + plane;
    float* outp = out + (size_t)bat * plane;

    const int rx  = reflect_i(cx, IMW);          // reflect-pad col (loads)
    const int lm2 = lane - 2, lm1 = lane - 1, lp1 = lane + 1, lp2 = lane + 2;
    const int ixm = (cx - 1 < 0 ? 0 : (cx - 1 >= IMW ? IMW - 1 : cx - 1)) - c0;
    const int ixp = (cx + 1 < 0 ? 0 : (cx + 1 >= IMW ? IMW - 1 : cx + 1)) - c0;

    const float w0 = 0.05448868f, w1 = 0.24420134f, w2 = 0.40261995f;

    // rolling rings
    float h0 = 0, h1 = 0, h2 = 0, h3 = 0;
    float b_1 = 0, b_0 = 0, bl_1 = 0, bl_0 = 0, br_1 = 0, br_0 = 0;
    float m_1 = 0, m_0 = 0, ml_1 = 0, ml_0 = 0, mr_1 = 0, mr_0 = 0;
    float gxp = 0, gyp = 0;

    auto process = [&](int yL, float gray) {
        float gm2 = __shfl(gray, lm2);
        float gm1 = __shfl(gray, lm1);
        float gp1 = __shfl(gray, lp1);
        float gp2 = __shfl(gray, lp2);
        float hnew = w0 * (gm2 + gp2) + w1 * (gm1 + gp1) + w2 * gray;
        float bnew = w0 * (h0 + hnew) + w1 * (h1 + h3) + w2 * h2;
        float blnew = __shfl(bnew, ixm);
        float brnew = __shfl(bnew, ixp);
        int u = yL - 3;
        float ta  = (u == 0) ? b_0 : b_1;
        float tla = (u == 0) ? bl_0 : bl_1;
        float tra = (u == 0) ? br_0 : br_1;
        float tb  = (u == IMH - 1) ? b_0 : bnew;
        float tlb = (u == IMH - 1) ? bl_0 : blnew;
        float trb = (u == IMH - 1) ? br_0 : brnew;
        float gx = (tra - tla) + 2.0f * (br_0 - bl_0) + (trb - tlb);
        float gy = (tlb - tla) + 2.0f * (tb - ta) + (trb - tra);
        float mnew = sqrtf(gx * gx + gy * gy + 1e-6f);
        if ((unsigned)cx >= (unsigned)IMW) mnew = 0.0f;
        float mlnew = __shfl(mnew, lm1);
        float mrnew = __shfl(mnew, lp1);
        int s = yL - 4;
        if (s >= y0) {
            float pm  = (s == 0) ? 0.0f : m_1;
            float pml = (s == 0) ? 0.0f : ml_1;
            float pmr = (s == 0) ? 0.0f : mr_1;
            float nm  = (s == IMH - 1) ? 0.0f : mnew;
            float nml = (s == IMH - 1) ? 0.0f : mlnew;
            float nmr = (s == IMH - 1) ? 0.0f : mrnew;
            float ax = fabsf(gxp), ay = fabsf(gyp);
            bool ew = (ay <= 0.41421356237f * ax);
            bool ns = (ay >= 2.41421356237f * ax);
            bool d1 = (gxp * gyp > 0.0f);
            float n1 = ew ? mr_0 : (ns ? nm : (d1 ? pmr : nmr));
            float n2 = ew ? ml_0 : (ns ? pm : (d1 ? nml : pml));
            float mag = m_0;
            float o = (mag > n1 && mag > n2) ? mag : 0.0f;
            if (lane >= 4 && lane < 60 && (unsigned)cx < (unsigned)IMW)
                __builtin_nontemporal_store(o, &outp[(size_t)s * IMW + cx]);
        }
        h0 = h1; h1 = h2; h2 = h3; h3 = hnew;
        b_1 = b_0;  b_0 = bnew;
        bl_1 = bl_0; bl_0 = blnew;
        br_1 = br_0; br_0 = brnew;
        m_1 = m_0;  m_0 = mnew;
        ml_1 = ml_0; ml_0 = mrnew * 0.0f + mlnew;  // (kept simple below)
        mr_1 = mr_0; mr_0 = mrnew;
        gxp = gx; gyp = gy;
    };

    // NOTE: fix the line above — no arithmetic tricks, plain rotate:
    // (the compiler folds it anyway, but keep exact semantics)
    // ml_0 must be mlnew. See rotation in-line.

    float rA[4], gA[4], cA[4], rB[4], gB[4], cB[4];
    int ybase = y0 - 4;
    #pragma unroll
    for (int r = 0; r < 4; ++r) {
        int yo = reflect_i(ybase + r, IMH) * IMW + rx;
        rA[r] = p0[yo]; gA[r] = p1[yo]; cA[r] = p2[yo];
    }

    for (int it = 0; it < 5; ++it) {
        // prefetch B: rows ybase+4 .. ybase+7 (12-load burst)
        #pragma unroll
        for (int r = 0; r < 4; ++r) {
            int yo = reflect_i(ybase + 4 + r, IMH) * IMW + rx;
            rB[r] = p0[yo]; gB[r] = p1[yo]; cB[r] = p2[yo];
        }
        // compute 4 rows from A
        #pragma unroll
        for (int r = 0; r < 4; ++r)
            process(ybase + r, 0.1495f * rA[r] + 0.2935f * gA[r] + 0.057f * cA[r] + 0.5f);
        // prefetch A: rows ybase+8 .. ybase+11
        if (it < 4) {
            #pragma unroll
            for (int r = 0; r < 4; ++r) {
                int yo = reflect_i(ybase + 8 + r, IMH) * IMW + rx;
                rA[r] = p0[yo]; gA[r] = p1[yo]; cA[r] = p2[yo];
            }
        }
        // compute 4 rows from B
        #pragma unroll
        for (int r = 0; r < 4; ++r)
            process(ybase + 4 + r, 0.1495f * rB[r] + 0.2935f * gB[r] + 0.057f * cB[r] + 0.5f);
        ybase += 8;
    }
}

extern "C" void kernel_launch(void* const* d_in, const int* in_sizes, int n_in,
                              void* d_out, int out_size, void* d_ws, size_t ws_size,
                              hipStream_t stream) {
    const float* data = (const float*)d_in[0];
    float* out = (float*)d_out;
    int B = in_sizes[0] / (3 * IMH * IMW);   // 16
    int blocks = (B * NBAND * NWC) / 4;      // 4 waves per 256-thread block
    canny_stream<<<blocks, dim3(256, 1, 1), 0, stream>>>(data, out);
}

// Round 7
// 93.214 us; speedup vs baseline: 1.0090x; 1.0090x over previous
//
#include <hip/hip_runtime.h>
#include <math.h>

#define IMH 512
#define IMW 512
#define RB    16    // output rows per wave-band
#define NBAND 32    // IMH / RB
#define NWC   10    // wave-columns: out width 56 each, c0 = 56*wc - 4
#define OUTW  56

__device__ __forceinline__ int reflect_i(int v, int n) {
    if (v < 0) v = -v;
    if (v >= n) v = 2 * n - 2 - v;
    return v;
}
// DPP wave shifts (VALU pipe, ~2cyc). Boundary lanes keep own value (don't-care:
// stores happen only in lanes 4..59 and their input cone never uses invalid shifts).
__device__ __forceinline__ float dpp_shr1(float x) {   // lane i <- lane i-1
    int i = __float_as_int(x);
    return __int_as_float(__builtin_amdgcn_update_dpp(i, i, 0x138, 0xF, 0xF, false));
}
__device__ __forceinline__ float dpp_shl1(float x) {   // lane i <- lane i+1
    int i = __float_as_int(x);
    return __int_as_float(__builtin_amdgcn_update_dpp(i, i, 0x130, 0xF, 0xF, false));
}

// One wave streams a 64-col x RB-row band. YB: band touches top/bottom image rows.
template <bool YB>
__device__ __forceinline__ void run_band(const float* __restrict__ p0,
                                         const float* __restrict__ p1,
                                         const float* __restrict__ p2,
                                         float* __restrict__ outp,
                                         int y0, int rx, int cx,
                                         int ixm, int ixp, int lane) {
    const float w0 = 0.05448868f, w1 = 0.24420134f, w2 = 0.40261995f;

    float h0 = 0, h1 = 0, h2 = 0, h3 = 0;
    float b_1 = 0, b_0 = 0, bl_1 = 0, bl_0 = 0, br_1 = 0, br_0 = 0;
    float m_1 = 0, m_0 = 0, ml_1 = 0, ml_0 = 0, mr_1 = 0, mr_0 = 0;
    float gxp = 0, gyp = 0;

    auto process = [&](int yL, float gray) {
        float gm1 = dpp_shr1(gray);
        float gm2 = dpp_shr1(gm1);
        float gp1 = dpp_shl1(gray);
        float gp2 = dpp_shl1(gp1);
        float hnew = w0 * (gm2 + gp2) + w1 * (gm1 + gp1) + w2 * gray;
        float bnew = w0 * (h0 + hnew) + w1 * (h1 + h3) + w2 * h2;
        float blnew = __shfl(bnew, ixm);   // edge-clamped col -1 (image border aware)
        float brnew = __shfl(bnew, ixp);   // edge-clamped col +1
        int u = yL - 3;
        float ta  = (YB && u == 0) ? b_0 : b_1;
        float tla = (YB && u == 0) ? bl_0 : bl_1;
        float tra = (YB && u == 0) ? br_0 : br_1;
        float tb  = (YB && u == IMH - 1) ? b_0 : bnew;
        float tlb = (YB && u == IMH - 1) ? bl_0 : blnew;
        float trb = (YB && u == IMH - 1) ? br_0 : brnew;
        float gx = (tra - tla) + 2.0f * (br_0 - bl_0) + (trb - tlb);
        float gy = (tlb - tla) + 2.0f * (tb - ta) + (trb - tra);
        float mnew = sqrtf(gx * gx + gy * gy + 1e-6f);
        if ((unsigned)cx >= (unsigned)IMW) mnew = 0.0f;   // NMS zero-pad cols
        float mlnew = dpp_shr1(mnew);
        float mrnew = dpp_shl1(mnew);
        int s = yL - 4;
        if (s >= y0) {
            float pm  = (YB && s == 0) ? 0.0f : m_1;
            float pml = (YB && s == 0) ? 0.0f : ml_1;
            float pmr = (YB && s == 0) ? 0.0f : mr_1;
            float nm  = (YB && s == IMH - 1) ? 0.0f : mnew;
            float nml = (YB && s == IMH - 1) ? 0.0f : mlnew;
            float nmr = (YB && s == IMH - 1) ? 0.0f : mrnew;
            float ax = fabsf(gxp), ay = fabsf(gyp);
            bool ew = (ay <= 0.41421356237f * ax);
            bool ns = (ay >= 2.41421356237f * ax);
            bool d1 = (gxp * gyp > 0.0f);
            float n1 = ew ? mr_0 : (ns ? nm : (d1 ? pmr : nmr));
            float n2 = ew ? ml_0 : (ns ? pm : (d1 ? nml : pml));
            float mag = m_0;
            float o = (mag > n1 && mag > n2) ? mag : 0.0f;
            if (lane >= 4 && lane < 60 && (unsigned)cx < (unsigned)IMW)
                __builtin_nontemporal_store(o, &outp[(size_t)s * IMW + cx]);
        }
        h0 = h1; h1 = h2; h2 = h3; h3 = hnew;
        b_1 = b_0;  b_0 = bnew;
        bl_1 = bl_0; bl_0 = blnew;
        br_1 = br_0; br_0 = brnew;
        m_1 = m_0;  m_0 = mnew;
        ml_1 = ml_0; ml_0 = mlnew;
        mr_1 = mr_0; mr_0 = mrnew;
        gxp = gx; gyp = gy;
    };

    // depth-2 prefetch (A/B), rows yL = y0-4 .. y0+RB+3
    int ya = reflect_i(y0 - 4, IMH) * IMW;
    float rA = p0[ya + rx], gA = p1[ya + rx], cA = p2[ya + rx];
    int yb = reflect_i(y0 - 3, IMH) * IMW;
    float rB = p0[yb + rx], gB = p1[yb + rx], cB = p2[yb + rx];

    #pragma unroll 2
    for (int tt = 0; tt < (RB + 8) / 2; ++tt) {
        int yL = y0 - 4 + 2 * tt;
        float grayA = 0.1495f * rA + 0.2935f * gA + 0.057f * cA + 0.5f;
        int yr = reflect_i(yL + 2, IMH) * IMW;
        rA = p0[yr + rx]; gA = p1[yr + rx]; cA = p2[yr + rx];
        process(yL, grayA);
        float grayB = 0.1495f * rB + 0.2935f * gB + 0.057f * cB + 0.5f;
        int yr2 = reflect_i(yL + 3, IMH) * IMW;
        rB = p0[yr2 + rx]; gB = p1[yr2 + rx]; cB = p2[yr2 + rx];
        process(yL + 1, grayB);
    }
}

__global__ __launch_bounds__(256)
void canny_stream(const float* __restrict__ data, float* __restrict__ out) {
    const int lane = threadIdx.x & 63;
    const int wid  = (blockIdx.x << 2) + (threadIdx.x >> 6);
    const int wc   = wid % NWC;
    const int t2   = wid / NWC;
    const int band = t2 & (NBAND - 1);
    const int bat  = t2 >> 5;            // t2 / NBAND

    const int c0 = OUTW * wc - 4;
    const int cx = c0 + lane;
    const int y0 = band * RB;

    const size_t plane = (size_t)(IMH * IMW);
    const float* p0 = data + (size_t)bat * 3 * plane;
    const float* p1 = p0 + plane;
    const float* p2 = p1 + plane;
    float* outp = out + (size_t)bat * plane;

    const int rx  = reflect_i(cx, IMW);
    const int ixm = (cx - 1 < 0 ? 0 : (cx - 1 >= IMW ? IMW - 1 : cx - 1)) - c0;
    const int ixp = (cx + 1 < 0 ? 0 : (cx + 1 >= IMW ? IMW - 1 : cx + 1)) - c0;

    if (band == 0 || band == NBAND - 1)
        run_band<true>(p0, p1, p2, outp, y0, rx, cx, ixm, ixp, lane);
    else
        run_band<false>(p0, p1, p2, outp, y0, rx, cx, ixm, ixp, lane);
}

extern "C" void kernel_launch(void* const* d_in, const int* in_sizes, int n_in,
                              void* d_out, int out_size, void* d_ws, size_t ws_size,
                              hipStream_t stream) {
    const float* data = (const float*)d_in[0];
    float* out = (float*)d_out;
    int B = in_sizes[0] / (3 * IMH * IMW);   // 16
    int blocks = (B * NBAND * NWC) / 4;      // 4 waves per 256-thread block
    canny_stream<<<blocks, dim3(256, 1, 1), 0, stream>>>(data, out);
}